// Round 3
// baseline (242.269 us; speedup 1.0000x reference)
//
#include <hip/hip_runtime.h>
#include <hip/hip_bf16.h>

typedef __bf16 bf16x8 __attribute__((ext_vector_type(8)));
typedef float f32x4 __attribute__((ext_vector_type(4)));

#define FEAT 2048
#define HID  1024
#define AD   512
#define NB   128
#define NP   196
#define MROWS (NB * NP)      // 25088
#define BM 128
#define BN 128
#define BK 64
#define NSTEP (FEAT / BK)    // 32
#define NBLK (MROWS / BM * 4) // 196 row-tiles x 4 n-quarters = 784

__device__ __forceinline__ void gload16(const void* g, void* l) {
    __builtin_amdgcn_global_load_lds(
        (const __attribute__((address_space(1))) void*)(g),
        (__attribute__((address_space(3))) void*)(l), 16, 0, 0);
}

// ---------------- pack We (fp32 [512][2048]) -> bf16 MFMA-fragment order ----------------
// For 16x16x32 MFMA, B-operand lane l needs We[nt*16 + (l&15)][kt*32 + (l>>4)*8 + e].
// Packed: off = ((kt*32 + nt)*64 + l)*8 + e  -> each (kt,nt) fragment is 1KB contiguous.
__global__ __launch_bounds__(256) void pack_we_k(const float* __restrict__ We,
                                                 __bf16* __restrict__ Bp) {
    int t = blockIdx.x * 256 + threadIdx.x;   // 131072 threads, 8 elems each
    int a  = t >> 8;
    int f0 = (t & 255) << 3;
    const float4* src = reinterpret_cast<const float4*>(We + ((size_t)a << 11) + f0);
    float4 x0 = src[0], x1 = src[1];
    int nt = a >> 4, r = a & 15;
    int kt = f0 >> 5, g = (f0 >> 3) & 3;
    size_t off = (((size_t)(kt * 32 + nt) * 64) + (r + (g << 4))) << 3;
    union { __bf16 h[8]; bf16x8 v; } u;
    u.h[0] = (__bf16)x0.x; u.h[1] = (__bf16)x0.y; u.h[2] = (__bf16)x0.z; u.h[3] = (__bf16)x0.w;
    u.h[4] = (__bf16)x1.x; u.h[5] = (__bf16)x1.y; u.h[6] = (__bf16)x1.z; u.h[7] = (__bf16)x1.w;
    *reinterpret_cast<bf16x8*>(Bp + off) = u.v;
}

// ---------------- dec[b][n] = hidden[b]·Wd[n] + bd[n] + be[n]  (fp32, exact) ------------
__global__ __launch_bounds__(256) void dec_k(const float* __restrict__ hidden,
                                             const float* __restrict__ Wd,
                                             const float* __restrict__ bd,
                                             const float* __restrict__ be,
                                             float* __restrict__ decb) {
    __shared__ float w[8][1028];
    const int tid = threadIdx.x;
    const int n0 = blockIdx.x << 3;
    const float4* wsrc = reinterpret_cast<const float4*>(Wd + ((size_t)n0 << 10));
    #pragma unroll
    for (int i = 0; i < 8; ++i)
        *reinterpret_cast<float4*>(&w[i][tid << 2]) = wsrc[(i << 8) + tid];
    __syncthreads();
    const int nl = tid & 7, b0 = tid >> 3;
    float acc[4] = {0.f, 0.f, 0.f, 0.f};
    const float4* wp = reinterpret_cast<const float4*>(&w[nl][0]);
    #pragma unroll 2
    for (int k4 = 0; k4 < 256; ++k4) {
        float4 wv = wp[k4];
        #pragma unroll
        for (int i = 0; i < 4; ++i) {
            const float4 h = reinterpret_cast<const float4*>(
                hidden + ((size_t)(b0 + (i << 5)) << 10))[k4];
            acc[i] = fmaf(wv.x, h.x, acc[i]);
            acc[i] = fmaf(wv.y, h.y, acc[i]);
            acc[i] = fmaf(wv.z, h.z, acc[i]);
            acc[i] = fmaf(wv.w, h.w, acc[i]);
        }
    }
    const float bias = bd[n0 + nl] + be[n0 + nl];
    #pragma unroll
    for (int i = 0; i < 4; ++i)
        decb[(size_t)(b0 + (i << 5)) * AD + n0 + nl] = acc[i] + bias;
}

// ---------------- main fused kernel: enc GEMM + tanh + Wf-dot -> partial scores ---------
__global__ __launch_bounds__(256, 3) void enc_score_k(
        const float* __restrict__ X, const __bf16* __restrict__ Bp,
        const float* __restrict__ decb, const float* __restrict__ Wf,
        float* __restrict__ spart) {
    __shared__ char Asm[BM * BK * 2];        // 16 KB, single-buffered (regs = 2nd buffer)
    __shared__ char Bsm[2][16384];           // 2 x 16 KB double-buffered
    __shared__ float swave[2][BM];
    const int tid  = threadIdx.x;
    const int wave = tid >> 6, lane = tid & 63;
    const int lr = lane & 15, lg = lane >> 4;
    const int wm = wave >> 1, wn = wave & 1;  // wave -> 64x64 quadrant
    // chunked XCD swizzle (784 = 8*98, bijective): same row-stripe stays on one XCD
    const int vbid = (blockIdx.x & 7) * 98 + (blockIdx.x >> 3);
    const int rt = vbid >> 2, nq = vbid & 3;
    const int row0 = rt * BM;
    const int ncol0 = nq * BN + wn * 64;      // this wave's global N base

    // acc init = dec[b][n]  (C/D layout: col=lane&15, row=(lane>>4)*4+j)
    f32x4 acc[4][4];
    #pragma unroll
    for (int mt = 0; mt < 4; ++mt) {
        #pragma unroll
        for (int j = 0; j < 4; ++j) {
            const int row = wm * 64 + mt * 16 + lg * 4 + j;
            const int b = (unsigned)(row0 + row) / 196u;
            const float* dp = decb + (size_t)b * AD + ncol0 + lr;
            #pragma unroll
            for (int nt = 0; nt < 4; ++nt) acc[mt][nt][j] = dp[nt * 16];
        }
    }

    // ---- A staging geometry: thread -> row=tid>>1, 32-float half sq=tid&1 ----
    const int srow = tid >> 1, sq = tid & 1;
    const float* gA = X + (size_t)(row0 + srow) * FEAT + sq * 32;
    const int swz = (srow & 7) << 4;
    char* awr = Asm + srow * 128;

    // ---- B staging geometry: wave stages chunks c0..c0+3 (1 KB each) ----
    const char* BpB = (const char*)Bp;
    const int c0 = wave * 4;
    int csrc[4];     // packed-B fragment row index per chunk
    #pragma unroll
    for (int i = 0; i < 4; ++i) {
        const int c = c0 + i;
        csrc[i] = (c >> 3) * 32 + nq * 8 + (c & 7);   // (kt2)*32 + global nt
    }

    const int rswz = (lr & 7) << 4;

    float4 r[8];
    // ---- prologue: A(0)->regs, B(0)->Bsm[0], A(0)->Asm, A(1)->regs ----
    {
        const float4* g = reinterpret_cast<const float4*>(gA);
        #pragma unroll
        for (int i = 0; i < 8; ++i) r[i] = g[i];
    }
    #pragma unroll
    for (int i = 0; i < 4; ++i)
        gload16(BpB + ((size_t)(csrc[i] << 6) + lane) * 16, Bsm[0] + (c0 + i) * 1024);
    #pragma unroll
    for (int u = 0; u < 4; ++u) {
        union { __bf16 h[8]; bf16x8 v; } p;
        p.h[0]=(__bf16)r[2*u].x; p.h[1]=(__bf16)r[2*u].y; p.h[2]=(__bf16)r[2*u].z; p.h[3]=(__bf16)r[2*u].w;
        p.h[4]=(__bf16)r[2*u+1].x; p.h[5]=(__bf16)r[2*u+1].y; p.h[6]=(__bf16)r[2*u+1].z; p.h[7]=(__bf16)r[2*u+1].w;
        *reinterpret_cast<bf16x8*>(awr + ((sq * 64 + u * 16) ^ swz)) = p.v;
    }
    {
        const float4* g = reinterpret_cast<const float4*>(gA + 64);
        #pragma unroll
        for (int i = 0; i < 8; ++i) r[i] = g[i];
    }
    asm volatile("s_waitcnt vmcnt(8) lgkmcnt(0)" ::: "memory");
    __builtin_amdgcn_s_barrier();

    int cur = 0;
    for (int t = 0; t < NSTEP; ++t) {
        // issue next-step B into the other buffer (flies across compute + barrier)
        if (t < NSTEP - 1) {
            const size_t kbase = (size_t)(2 * (t + 1)) * 32 * 1024;  // 2 kts per step, 1KB/frag-row
            #pragma unroll
            for (int i = 0; i < 4; ++i)
                gload16(BpB + kbase + ((size_t)(csrc[i] << 6) + lane) * 16,
                        Bsm[cur ^ 1] + (c0 + i) * 1024);
        }
        // compute current step: 2 kt2 x (4 B-frags, 4 A-frags, 16 MFMA)
        #pragma unroll
        for (int kt2 = 0; kt2 < 2; ++kt2) {
            bf16x8 bfr[4];
            #pragma unroll
            for (int j = 0; j < 4; ++j)
                bfr[j] = *reinterpret_cast<const bf16x8*>(
                    Bsm[cur] + ((kt2 * 8 + wn * 4 + j) * 64 + lane) * 16);
            #pragma unroll
            for (int mt = 0; mt < 4; ++mt) {
                bf16x8 a = *reinterpret_cast<const bf16x8*>(
                    Asm + (wm * 64 + mt * 16 + lr) * 128 + ((kt2 * 64 + lg * 16) ^ rswz));
                acc[mt][0] = __builtin_amdgcn_mfma_f32_16x16x32_bf16(a, bfr[0], acc[mt][0], 0, 0, 0);
                acc[mt][1] = __builtin_amdgcn_mfma_f32_16x16x32_bf16(a, bfr[1], acc[mt][1], 0, 0, 0);
                acc[mt][2] = __builtin_amdgcn_mfma_f32_16x16x32_bf16(a, bfr[2], acc[mt][2], 0, 0, 0);
                acc[mt][3] = __builtin_amdgcn_mfma_f32_16x16x32_bf16(a, bfr[3], acc[mt][3], 0, 0, 0);
            }
        }
        if (t < NSTEP - 1) {
            __builtin_amdgcn_s_barrier();     // all waves done reading Asm
            // write A(t+1) regs -> Asm (compiler waits the A-loads via vmcnt)
            #pragma unroll
            for (int u = 0; u < 4; ++u) {
                union { __bf16 h[8]; bf16x8 v; } p;
                p.h[0]=(__bf16)r[2*u].x; p.h[1]=(__bf16)r[2*u].y; p.h[2]=(__bf16)r[2*u].z; p.h[3]=(__bf16)r[2*u].w;
                p.h[4]=(__bf16)r[2*u+1].x; p.h[5]=(__bf16)r[2*u+1].y; p.h[6]=(__bf16)r[2*u+1].z; p.h[7]=(__bf16)r[2*u+1].w;
                *reinterpret_cast<bf16x8*>(awr + ((sq * 64 + u * 16) ^ swz)) = p.v;
            }
            if (t < NSTEP - 2) {              // prefetch A(t+2) -> regs
                const float4* g = reinterpret_cast<const float4*>(gA + (size_t)(t + 2) * BK);
                #pragma unroll
                for (int i = 0; i < 8; ++i) r[i] = g[i];
                // counted drain: oldest 4 (B gload_lds) done; 8 A loads stay in flight
                asm volatile("s_waitcnt vmcnt(8) lgkmcnt(0)" ::: "memory");
            } else {
                asm volatile("s_waitcnt vmcnt(0) lgkmcnt(0)" ::: "memory");
            }
            __builtin_amdgcn_s_barrier();
            cur ^= 1;
        }
    }

    // epilogue: partial score = sum_{n in this 128-col quarter} tanh(acc)*Wf[n]
    float wf[4];
    #pragma unroll
    for (int nt = 0; nt < 4; ++nt) wf[nt] = Wf[ncol0 + nt * 16 + lr];
    #pragma unroll
    for (int mt = 0; mt < 4; ++mt) {
        #pragma unroll
        for (int j = 0; j < 4; ++j) {
            float s = 0.f;
            #pragma unroll
            for (int nt = 0; nt < 4; ++nt) {
                float x = acc[mt][nt][j];
                float e = __expf(2.0f * x);
                float t = 1.0f - 2.0f / (e + 1.0f);   // tanh, no-NaN at +/-inf
                s = fmaf(t, wf[nt], s);
            }
            s += __shfl_xor(s, 1); s += __shfl_xor(s, 2);
            s += __shfl_xor(s, 4); s += __shfl_xor(s, 8);
            if (lr == 0) swave[wn][wm * 64 + mt * 16 + lg * 4 + j] = s;
        }
    }
    __syncthreads();
    if (tid < BM)
        spart[(size_t)nq * MROWS + row0 + tid] = swave[0][tid] + swave[1][tid];
}

// ---------------- softmax over P=196 per batch row (sums 4 N-quarter partials) ----------
__global__ __launch_bounds__(64) void softmax_k(const float* __restrict__ spart,
                                                float* __restrict__ alpha) {
    const int b = blockIdx.x, lane = threadIdx.x;
    float v[4], e[4];
    float m = -3.0e38f;
    #pragma unroll
    for (int i = 0; i < 4; ++i) {
        int p = i * 64 + lane;
        if (p < NP) {
            int idx = b * NP + p;
            v[i] = spart[idx] + spart[MROWS + idx] + spart[2 * MROWS + idx]
                 + spart[3 * MROWS + idx];
        } else v[i] = -3.0e38f;
        m = fmaxf(m, v[i]);
    }
    #pragma unroll
    for (int o = 1; o < 64; o <<= 1) m = fmaxf(m, __shfl_xor(m, o));
    float s = 0.f;
    #pragma unroll
    for (int i = 0; i < 4; ++i) {
        int p = i * 64 + lane;
        e[i] = (p < NP) ? __expf(v[i] - m) : 0.f;
        s += e[i];
    }
    #pragma unroll
    for (int o = 1; o < 64; o <<= 1) s += __shfl_xor(s, o);
    const float inv = 1.0f / s;
    #pragma unroll
    for (int i = 0; i < 4; ++i) {
        int p = i * 64 + lane;
        if (p < NP) alpha[b * NP + p] = e[i] * inv;
    }
}

// ---------------- context[b][f] = sum_p alpha[b][p] * X[b][p][f]  (fp32) ----------------
__global__ __launch_bounds__(128) void context_k(const float* __restrict__ X,
                                                 const float* __restrict__ alpha,
                                                 float* __restrict__ ctx) {
    __shared__ float al[NP];
    const int bid = blockIdx.x;
    const int b = 127 - (bid >> 2);
    const int chunk = bid & 3;
    const int tid = threadIdx.x;
    for (int i = tid; i < NP; i += 128) al[i] = alpha[b * NP + i];
    __syncthreads();
    const float4* Xp = reinterpret_cast<const float4*>(X + (size_t)b * NP * FEAT)
                       + chunk * 128 + tid;
    float4 a0 = {0,0,0,0}, a1 = {0,0,0,0};
    #pragma unroll 4
    for (int p = 0; p < NP; p += 2) {
        const float w0 = al[p], w1 = al[p + 1];
        const float4 x0 = Xp[(size_t)p * 512];
        const float4 x1 = Xp[(size_t)(p + 1) * 512];
        a0.x = fmaf(w0, x0.x, a0.x); a0.y = fmaf(w0, x0.y, a0.y);
        a0.z = fmaf(w0, x0.z, a0.z); a0.w = fmaf(w0, x0.w, a0.w);
        a1.x = fmaf(w1, x1.x, a1.x); a1.y = fmaf(w1, x1.y, a1.y);
        a1.z = fmaf(w1, x1.z, a1.z); a1.w = fmaf(w1, x1.w, a1.w);
    }
    float4 rr; rr.x = a0.x + a1.x; rr.y = a0.y + a1.y; rr.z = a0.z + a1.z; rr.w = a0.w + a1.w;
    *reinterpret_cast<float4*>(ctx + (size_t)b * FEAT + chunk * 512 + tid * 4) = rr;
}

extern "C" void kernel_launch(void* const* d_in, const int* in_sizes, int n_in,
                              void* d_out, int out_size, void* d_ws, size_t ws_size,
                              hipStream_t stream) {
    const float* enc    = (const float*)d_in[0];
    const float* hidden = (const float*)d_in[1];
    const float* We     = (const float*)d_in[2];
    const float* be     = (const float*)d_in[3];
    const float* Wd     = (const float*)d_in[4];
    const float* bd     = (const float*)d_in[5];
    const float* Wf     = (const float*)d_in[6];
    // d_in[7] = bf: additive constant to all scores -> softmax-invariant, unused.

    float* out   = (float*)d_out;
    float* ctx   = out;                  // [128*2048]
    float* alpha = out + NB * FEAT;      // [128*196]

    char* ws = (char*)d_ws;
    __bf16* Bp    = (__bf16*)ws;                                   // 2 MB packed We
    float*  decb  = (float*)(ws + (2u << 20));                     // 256 KB
    float*  spart = (float*)(ws + (2u << 20) + (256u << 10));      // 4 x 100 KB partials

    pack_we_k  <<<dim3(512), dim3(256), 0, stream>>>(We, Bp);
    dec_k      <<<dim3(64),  dim3(256), 0, stream>>>(hidden, Wd, bd, be, decb);
    enc_score_k<<<dim3(NBLK), dim3(256), 0, stream>>>(enc, Bp, decb, Wf, spart);
    softmax_k  <<<dim3(NB),  dim3(64),  0, stream>>>(spart, alpha);
    context_k  <<<dim3(512), dim3(128), 0, stream>>>(enc, alpha, ctx);
}

// Round 4
// 192.156 us; speedup vs baseline: 1.2608x; 1.2608x over previous
//
#include <hip/hip_runtime.h>
#include <hip/hip_bf16.h>

typedef __bf16 bf16x8 __attribute__((ext_vector_type(8)));
typedef __bf16 bf16x4 __attribute__((ext_vector_type(4)));
typedef float f32x4 __attribute__((ext_vector_type(4)));

#define FEAT 2048
#define HID  1024
#define AD   512
#define NB   128
#define NP   196
#define MROWS (NB * NP)      // 25088
#define BM 128
#define BN 128
#define BK 64
#define NSTEP (FEAT / BK)    // 32
#define NBLK (MROWS / BM * 4) // 196 row-tiles x 4 n-quarters = 784

// ---------------- pack We (fp32 [512][2048]) -> bf16 MFMA-fragment order ----------------
// For 16x16x32 MFMA, B-operand lane l needs We[nt*16 + (l&15)][kt*32 + (l>>4)*8 + e].
// Packed: off = ((kt*32 + nt)*64 + l)*8 + e  -> each (kt,nt) fragment is 1KB contiguous.
__global__ __launch_bounds__(256) void pack_we_k(const float* __restrict__ We,
                                                 __bf16* __restrict__ Bp) {
    int t = blockIdx.x * 256 + threadIdx.x;   // 131072 threads, 8 elems each
    int a  = t >> 8;
    int f0 = (t & 255) << 3;
    const float4* src = reinterpret_cast<const float4*>(We + ((size_t)a << 11) + f0);
    float4 x0 = src[0], x1 = src[1];
    int nt = a >> 4, r = a & 15;
    int kt = f0 >> 5, g = (f0 >> 3) & 3;
    size_t off = (((size_t)(kt * 32 + nt) * 64) + (r + (g << 4))) << 3;
    union { __bf16 h[8]; bf16x8 v; } u;
    u.h[0] = (__bf16)x0.x; u.h[1] = (__bf16)x0.y; u.h[2] = (__bf16)x0.z; u.h[3] = (__bf16)x0.w;
    u.h[4] = (__bf16)x1.x; u.h[5] = (__bf16)x1.y; u.h[6] = (__bf16)x1.z; u.h[7] = (__bf16)x1.w;
    *reinterpret_cast<bf16x8*>(Bp + off) = u.v;
}

// ---------------- dec[b][n] = hidden[b]·Wd[n] + bd[n] + be[n]  (fp32, exact) ------------
__global__ __launch_bounds__(256) void dec_k(const float* __restrict__ hidden,
                                             const float* __restrict__ Wd,
                                             const float* __restrict__ bd,
                                             const float* __restrict__ be,
                                             float* __restrict__ decb) {
    __shared__ float w[8][1028];
    const int tid = threadIdx.x;
    const int n0 = blockIdx.x << 3;
    const float4* wsrc = reinterpret_cast<const float4*>(Wd + ((size_t)n0 << 10));
    #pragma unroll
    for (int i = 0; i < 8; ++i)
        *reinterpret_cast<float4*>(&w[i][tid << 2]) = wsrc[(i << 8) + tid];
    __syncthreads();
    const int nl = tid & 7, b0 = tid >> 3;
    float acc[4] = {0.f, 0.f, 0.f, 0.f};
    const float4* wp = reinterpret_cast<const float4*>(&w[nl][0]);
    #pragma unroll 2
    for (int k4 = 0; k4 < 256; ++k4) {
        float4 wv = wp[k4];
        #pragma unroll
        for (int i = 0; i < 4; ++i) {
            const float4 h = reinterpret_cast<const float4*>(
                hidden + ((size_t)(b0 + (i << 5)) << 10))[k4];
            acc[i] = fmaf(wv.x, h.x, acc[i]);
            acc[i] = fmaf(wv.y, h.y, acc[i]);
            acc[i] = fmaf(wv.z, h.z, acc[i]);
            acc[i] = fmaf(wv.w, h.w, acc[i]);
        }
    }
    const float bias = bd[n0 + nl] + be[n0 + nl];
    #pragma unroll
    for (int i = 0; i < 4; ++i)
        decb[(size_t)(b0 + (i << 5)) * AD + n0 + nl] = acc[i] + bias;
}

// ---------------- main fused kernel: enc GEMM + tanh + Wf-dot -> partial scores ---------
__global__ __launch_bounds__(256, 3) void enc_score_k(
        const float* __restrict__ X, const __bf16* __restrict__ Bp,
        const float* __restrict__ decb, const float* __restrict__ Wf,
        float* __restrict__ spart) {
    __shared__ char Asm[2][BM * BK * 2];      // 2 x 16 KB double-buffered bf16 A
    __shared__ float swave[2][BM];
    const int tid  = threadIdx.x;
    const int wave = tid >> 6, lane = tid & 63;
    const int lr = lane & 15, lg = lane >> 4;
    const int wm = wave >> 1, wn = wave & 1;  // wave -> 64x64 quadrant
    // chunked XCD swizzle (784 = 8*98, bijective): same row-stripe stays on one XCD
    const int vbid = (blockIdx.x & 7) * 98 + (blockIdx.x >> 3);
    const int rt = vbid >> 2, nq = vbid & 3;
    const int row0 = rt * BM;
    const int ncol0 = nq * BN + wn * 64;      // this wave's global N base

    // acc init = dec[b][n]  (C/D layout: col=lane&15, row=(lane>>4)*4+j)
    f32x4 acc[4][4];
    #pragma unroll
    for (int mt = 0; mt < 4; ++mt) {
        #pragma unroll
        for (int j = 0; j < 4; ++j) {
            const int row = wm * 64 + mt * 16 + lg * 4 + j;
            const int b = (unsigned)(row0 + row) / 196u;
            const float* dp = decb + (size_t)b * AD + ncol0 + lr;
            #pragma unroll
            for (int nt = 0; nt < 4; ++nt) acc[mt][nt][j] = dp[nt * 16];
        }
    }

    // ---- A staging geometry (wave-contiguous): instr i covers rows (tid>>4)+16i,
    //      lane chunk (tid&15)*16B -> 64 lanes = 4 x 256B contiguous segments = 8 lines ----
    const int srow = tid >> 4;                // base row 0..15
    const int schk = tid & 15;                // 16B chunk within 256B row-segment
    const float* gA = X + (size_t)(row0 + srow) * FEAT + schk * 4;
    // ds_write target per i: row r = srow+16i, byte col = schk*8, XOR-swizzled
    // frag-read swizzle (same scheme: byte ^= (row&7)<<4)
    const int rswz = (lr & 7) << 4;
    // B fragments: packed Bp, frag(kt,nt) at byte (kt*32+nt)*1024 + lane*16
    const __bf16* Bq = Bp + ((size_t)(nq * 8 + wn * 4) << 9) + (lane << 3);

    float4 rA[8];
    // ---- prologue: stage A(0) ----
    #pragma unroll
    for (int i = 0; i < 8; ++i)
        rA[i] = *reinterpret_cast<const float4*>(gA + (size_t)(i * 16) * FEAT);
    #pragma unroll
    for (int i = 0; i < 8; ++i) {
        const int r = srow + 16 * i;
        union { __bf16 h[4]; bf16x4 v; } p;
        p.h[0] = (__bf16)rA[i].x; p.h[1] = (__bf16)rA[i].y;
        p.h[2] = (__bf16)rA[i].z; p.h[3] = (__bf16)rA[i].w;
        *reinterpret_cast<bf16x4*>(Asm[0] + r * 128 + ((schk * 8) ^ ((r & 7) << 4))) = p.v;
    }
    __syncthreads();

    int cur = 0;
    for (int t = 0; t < NSTEP; ++t) {
        // 1. prefetch A(t+1) -> regs (completes under compute; drained at barrier)
        if (t + 1 < NSTEP) {
            const float* g = gA + (size_t)(t + 1) * BK;
            #pragma unroll
            for (int i = 0; i < 8; ++i)
                rA[i] = *reinterpret_cast<const float4*>(g + (size_t)(i * 16) * FEAT);
        }
        // 2. compute step t from Asm[cur] + JIT B fragments (L2-resident, 1KB contiguous)
        #pragma unroll
        for (int kt2 = 0; kt2 < 2; ++kt2) {
            const size_t kt = 2 * t + kt2;
            bf16x8 bfr[4];
            #pragma unroll
            for (int j = 0; j < 4; ++j)
                bfr[j] = *reinterpret_cast<const bf16x8*>(Bq + kt * 16384 + j * 512);
            #pragma unroll
            for (int mt = 0; mt < 4; ++mt) {
                const int R = wm * 64 + mt * 16 + lr;
                bf16x8 a = *reinterpret_cast<const bf16x8*>(
                    Asm[cur] + R * 128 + ((kt2 * 64 + lg * 16) ^ rswz));
                acc[mt][0] = __builtin_amdgcn_mfma_f32_16x16x32_bf16(a, bfr[0], acc[mt][0], 0, 0, 0);
                acc[mt][1] = __builtin_amdgcn_mfma_f32_16x16x32_bf16(a, bfr[1], acc[mt][1], 0, 0, 0);
                acc[mt][2] = __builtin_amdgcn_mfma_f32_16x16x32_bf16(a, bfr[2], acc[mt][2], 0, 0, 0);
                acc[mt][3] = __builtin_amdgcn_mfma_f32_16x16x32_bf16(a, bfr[3], acc[mt][3], 0, 0, 0);
            }
        }
        // 3. cvt + write A(t+1) into the other buffer (no pre-barrier needed: dbuf)
        if (t + 1 < NSTEP) {
            #pragma unroll
            for (int i = 0; i < 8; ++i) {
                const int r = srow + 16 * i;
                union { __bf16 h[4]; bf16x4 v; } p;
                p.h[0] = (__bf16)rA[i].x; p.h[1] = (__bf16)rA[i].y;
                p.h[2] = (__bf16)rA[i].z; p.h[3] = (__bf16)rA[i].w;
                *reinterpret_cast<bf16x4*>(
                    Asm[cur ^ 1] + r * 128 + ((schk * 8) ^ ((r & 7) << 4))) = p.v;
            }
        }
        __syncthreads();
        cur ^= 1;
    }

    // epilogue: partial score = sum_{n in this 128-col quarter} tanh(acc)*Wf[n]
    float wf[4];
    #pragma unroll
    for (int nt = 0; nt < 4; ++nt) wf[nt] = Wf[ncol0 + nt * 16 + lr];
    #pragma unroll
    for (int mt = 0; mt < 4; ++mt) {
        #pragma unroll
        for (int j = 0; j < 4; ++j) {
            float s = 0.f;
            #pragma unroll
            for (int nt = 0; nt < 4; ++nt) {
                float x = acc[mt][nt][j];
                float e = __expf(2.0f * x);
                float t = 1.0f - 2.0f / (e + 1.0f);   // tanh, no-NaN at +/-inf
                s = fmaf(t, wf[nt], s);
            }
            s += __shfl_xor(s, 1); s += __shfl_xor(s, 2);
            s += __shfl_xor(s, 4); s += __shfl_xor(s, 8);
            if (lr == 0) swave[wn][wm * 64 + mt * 16 + lg * 4 + j] = s;
        }
    }
    __syncthreads();
    if (tid < BM)
        spart[(size_t)nq * MROWS + row0 + tid] = swave[0][tid] + swave[1][tid];
}

// ---------------- softmax over P=196 per batch row (sums 4 N-quarter partials) ----------
__global__ __launch_bounds__(64) void softmax_k(const float* __restrict__ spart,
                                                float* __restrict__ alpha) {
    const int b = blockIdx.x, lane = threadIdx.x;
    float v[4], e[4];
    float m = -3.0e38f;
    #pragma unroll
    for (int i = 0; i < 4; ++i) {
        int p = i * 64 + lane;
        if (p < NP) {
            int idx = b * NP + p;
            v[i] = spart[idx] + spart[MROWS + idx] + spart[2 * MROWS + idx]
                 + spart[3 * MROWS + idx];
        } else v[i] = -3.0e38f;
        m = fmaxf(m, v[i]);
    }
    #pragma unroll
    for (int o = 1; o < 64; o <<= 1) m = fmaxf(m, __shfl_xor(m, o));
    float s = 0.f;
    #pragma unroll
    for (int i = 0; i < 4; ++i) {
        int p = i * 64 + lane;
        e[i] = (p < NP) ? __expf(v[i] - m) : 0.f;
        s += e[i];
    }
    #pragma unroll
    for (int o = 1; o < 64; o <<= 1) s += __shfl_xor(s, o);
    const float inv = 1.0f / s;
    #pragma unroll
    for (int i = 0; i < 4; ++i) {
        int p = i * 64 + lane;
        if (p < NP) alpha[b * NP + p] = e[i] * inv;
    }
}

// ---------------- context[b][f] = sum_p alpha[b][p] * X[b][p][f]  (fp32) ----------------
__global__ __launch_bounds__(128) void context_k(const float* __restrict__ X,
                                                 const float* __restrict__ alpha,
                                                 float* __restrict__ ctx) {
    __shared__ float al[NP];
    const int bid = blockIdx.x;
    const int b = 127 - (bid >> 2);
    const int chunk = bid & 3;
    const int tid = threadIdx.x;
    for (int i = tid; i < NP; i += 128) al[i] = alpha[b * NP + i];
    __syncthreads();
    const float4* Xp = reinterpret_cast<const float4*>(X + (size_t)b * NP * FEAT)
                       + chunk * 128 + tid;
    float4 a0 = {0,0,0,0}, a1 = {0,0,0,0};
    #pragma unroll 4
    for (int p = 0; p < NP; p += 2) {
        const float w0 = al[p], w1 = al[p + 1];
        const float4 x0 = Xp[(size_t)p * 512];
        const float4 x1 = Xp[(size_t)(p + 1) * 512];
        a0.x = fmaf(w0, x0.x, a0.x); a0.y = fmaf(w0, x0.y, a0.y);
        a0.z = fmaf(w0, x0.z, a0.z); a0.w = fmaf(w0, x0.w, a0.w);
        a1.x = fmaf(w1, x1.x, a1.x); a1.y = fmaf(w1, x1.y, a1.y);
        a1.z = fmaf(w1, x1.z, a1.z); a1.w = fmaf(w1, x1.w, a1.w);
    }
    float4 rr; rr.x = a0.x + a1.x; rr.y = a0.y + a1.y; rr.z = a0.z + a1.z; rr.w = a0.w + a1.w;
    *reinterpret_cast<float4*>(ctx + (size_t)b * FEAT + chunk * 512 + tid * 4) = rr;
}

extern "C" void kernel_launch(void* const* d_in, const int* in_sizes, int n_in,
                              void* d_out, int out_size, void* d_ws, size_t ws_size,
                              hipStream_t stream) {
    const float* enc    = (const float*)d_in[0];
    const float* hidden = (const float*)d_in[1];
    const float* We     = (const float*)d_in[2];
    const float* be     = (const float*)d_in[3];
    const float* Wd     = (const float*)d_in[4];
    const float* bd     = (const float*)d_in[5];
    const float* Wf     = (const float*)d_in[6];
    // d_in[7] = bf: additive constant to all scores -> softmax-invariant, unused.

    float* out   = (float*)d_out;
    float* ctx   = out;                  // [128*2048]
    float* alpha = out + NB * FEAT;      // [128*196]

    char* ws = (char*)d_ws;
    __bf16* Bp    = (__bf16*)ws;                                   // 2 MB packed We
    float*  decb  = (float*)(ws + (2u << 20));                     // 256 KB
    float*  spart = (float*)(ws + (2u << 20) + (256u << 10));      // 4 x 100 KB partials

    pack_we_k  <<<dim3(512), dim3(256), 0, stream>>>(We, Bp);
    dec_k      <<<dim3(64),  dim3(256), 0, stream>>>(hidden, Wd, bd, be, decb);
    enc_score_k<<<dim3(NBLK), dim3(256), 0, stream>>>(enc, Bp, decb, Wf, spart);
    softmax_k  <<<dim3(NB),  dim3(64),  0, stream>>>(spart, alpha);
    context_k  <<<dim3(512), dim3(128), 0, stream>>>(enc, alpha, ctx);
}

// Round 5
// 174.121 us; speedup vs baseline: 1.3914x; 1.1036x over previous
//
#include <hip/hip_runtime.h>
#include <hip/hip_bf16.h>

typedef __bf16 bf16x8 __attribute__((ext_vector_type(8)));
typedef __bf16 bf16x4 __attribute__((ext_vector_type(4)));
typedef float f32x4 __attribute__((ext_vector_type(4)));

#define FEAT 2048
#define HID  1024
#define AD   512
#define NB   128
#define NP   196
#define MROWS (NB * NP)      // 25088
#define BM 128
#define BN 128
#define BK 64
#define NSTEP (FEAT / BK)    // 32
#define NBLK (MROWS / BM * 4) // 196 row-tiles x 4 n-quarters = 784

// ---------------- pack We (fp32 [512][2048]) -> bf16 MFMA-fragment order ----------------
// For 16x16x32 MFMA, B-operand lane l needs We[nt*16 + (l&15)][kt*32 + (l>>4)*8 + e].
// Packed: off = ((kt*32 + nt)*64 + l)*8 + e  -> each (kt,nt) fragment is 1KB contiguous.
__global__ __launch_bounds__(256) void pack_we_k(const float* __restrict__ We,
                                                 __bf16* __restrict__ Bp) {
    int t = blockIdx.x * 256 + threadIdx.x;   // 131072 threads, 8 elems each
    int a  = t >> 8;
    int f0 = (t & 255) << 3;
    const float4* src = reinterpret_cast<const float4*>(We + ((size_t)a << 11) + f0);
    float4 x0 = src[0], x1 = src[1];
    int nt = a >> 4, r = a & 15;
    int kt = f0 >> 5, g = (f0 >> 3) & 3;
    size_t off = (((size_t)(kt * 32 + nt) * 64) + (r + (g << 4))) << 3;
    union { __bf16 h[8]; bf16x8 v; } u;
    u.h[0] = (__bf16)x0.x; u.h[1] = (__bf16)x0.y; u.h[2] = (__bf16)x0.z; u.h[3] = (__bf16)x0.w;
    u.h[4] = (__bf16)x1.x; u.h[5] = (__bf16)x1.y; u.h[6] = (__bf16)x1.z; u.h[7] = (__bf16)x1.w;
    *reinterpret_cast<bf16x8*>(Bp + off) = u.v;
}

// ---------------- dec[b][n] = hidden[b]·Wd[n] + bd[n] + be[n]  (fp32, exact) ------------
__global__ __launch_bounds__(256) void dec_k(const float* __restrict__ hidden,
                                             const float* __restrict__ Wd,
                                             const float* __restrict__ bd,
                                             const float* __restrict__ be,
                                             float* __restrict__ decb) {
    __shared__ float w[8][1028];
    const int tid = threadIdx.x;
    const int n0 = blockIdx.x << 3;
    const float4* wsrc = reinterpret_cast<const float4*>(Wd + ((size_t)n0 << 10));
    #pragma unroll
    for (int i = 0; i < 8; ++i)
        *reinterpret_cast<float4*>(&w[i][tid << 2]) = wsrc[(i << 8) + tid];
    __syncthreads();
    const int nl = tid & 7, b0 = tid >> 3;
    float acc[4] = {0.f, 0.f, 0.f, 0.f};
    const float4* wp = reinterpret_cast<const float4*>(&w[nl][0]);
    #pragma unroll 2
    for (int k4 = 0; k4 < 256; ++k4) {
        float4 wv = wp[k4];
        #pragma unroll
        for (int i = 0; i < 4; ++i) {
            const float4 h = reinterpret_cast<const float4*>(
                hidden + ((size_t)(b0 + (i << 5)) << 10))[k4];
            acc[i] = fmaf(wv.x, h.x, acc[i]);
            acc[i] = fmaf(wv.y, h.y, acc[i]);
            acc[i] = fmaf(wv.z, h.z, acc[i]);
            acc[i] = fmaf(wv.w, h.w, acc[i]);
        }
    }
    const float bias = bd[n0 + nl] + be[n0 + nl];
    #pragma unroll
    for (int i = 0; i < 4; ++i)
        decb[(size_t)(b0 + (i << 5)) * AD + n0 + nl] = acc[i] + bias;
}

// ---------------- main fused kernel: enc GEMM + tanh + Wf-dot -> partial scores ---------
__global__ __launch_bounds__(256, 3) void enc_score_k(
        const float* __restrict__ X, const __bf16* __restrict__ Bp,
        const float* __restrict__ decb, const float* __restrict__ Wf,
        float* __restrict__ spart) {
    __shared__ char Asm[2][BM * BK * 2];      // 2 x 16 KB double-buffered bf16 A
    __shared__ float swave[2][BM];
    const int tid  = threadIdx.x;
    const int wave = tid >> 6, lane = tid & 63;
    const int lr = lane & 15, lg = lane >> 4;
    const int wm = wave >> 1, wn = wave & 1;  // wave -> 64x64 quadrant
    // chunked XCD swizzle (784 = 8*98, bijective): same row-stripe stays on one XCD
    const int vbid = (blockIdx.x & 7) * 98 + (blockIdx.x >> 3);
    const int rt = vbid >> 2, nq = vbid & 3;
    const int row0 = rt * BM;
    const int ncol0 = nq * BN + wn * 64;      // this wave's global N base

    // acc init = dec[b][n]  (C/D layout: col=lane&15, row=(lane>>4)*4+j)
    f32x4 acc[4][4];
    #pragma unroll
    for (int mt = 0; mt < 4; ++mt) {
        #pragma unroll
        for (int j = 0; j < 4; ++j) {
            const int row = wm * 64 + mt * 16 + lg * 4 + j;
            const int b = (unsigned)(row0 + row) / 196u;
            const float* dp = decb + (size_t)b * AD + ncol0 + lr;
            #pragma unroll
            for (int nt = 0; nt < 4; ++nt) acc[mt][nt][j] = dp[nt * 16];
        }
    }

    // ---- A staging geometry (wave-contiguous): instr i covers rows (tid>>4)+16i,
    //      lane chunk (tid&15)*16B -> 64 lanes = 4 x 256B contiguous segments = 8 lines ----
    const int srow = tid >> 4;                // base row 0..15
    const int schk = tid & 15;                // 16B chunk within 256B row-segment
    const float* gA = X + (size_t)(row0 + srow) * FEAT + schk * 4;
    const int rswz = (lr & 7) << 4;
    // B fragments: packed Bp, frag(kt,nt) at byte (kt*32+nt)*1024 + lane*16
    const __bf16* Bq = Bp + ((size_t)(nq * 8 + wn * 4) << 9) + (lane << 3);

    float4 rA[8];
    // ---- prologue: stage A(0) ----
    #pragma unroll
    for (int i = 0; i < 8; ++i)
        rA[i] = *reinterpret_cast<const float4*>(gA + (size_t)(i * 16) * FEAT);
    #pragma unroll
    for (int i = 0; i < 8; ++i) {
        const int r = srow + 16 * i;
        union { __bf16 h[4]; bf16x4 v; } p;
        p.h[0] = (__bf16)rA[i].x; p.h[1] = (__bf16)rA[i].y;
        p.h[2] = (__bf16)rA[i].z; p.h[3] = (__bf16)rA[i].w;
        *reinterpret_cast<bf16x4*>(Asm[0] + r * 128 + ((schk * 8) ^ ((r & 7) << 4))) = p.v;
    }
    __syncthreads();

    int cur = 0;
    for (int t = 0; t < NSTEP; ++t) {
        // 1. B fragment loads FIRST (L2-hot, oldest in vmcnt FIFO -> counted wait
        //    for MFMA does NOT drain the slow A loads issued after them)
        bf16x8 bfr[8];
        {
            const __bf16* bs = Bq + (size_t)t * 32768;
            #pragma unroll
            for (int kt2 = 0; kt2 < 2; ++kt2)
                #pragma unroll
                for (int j = 0; j < 4; ++j)
                    bfr[kt2 * 4 + j] = *reinterpret_cast<const bf16x8*>(
                        bs + kt2 * 16384 + j * 512);
        }
        __builtin_amdgcn_sched_barrier(0);
        // 2. A(t+1) prefetch (slow HBM/L3; youngest in FIFO -> stays in flight
        //    through the whole MFMA phase, drained only at the ds_write below)
        if (t + 1 < NSTEP) {
            const float* g = gA + (size_t)(t + 1) * BK;
            #pragma unroll
            for (int i = 0; i < 8; ++i)
                rA[i] = *reinterpret_cast<const float4*>(g + (size_t)(i * 16) * FEAT);
        }
        __builtin_amdgcn_sched_barrier(0);
        // 3. compute step t from Asm[cur] (compiler emits counted vmcnt for bfr only)
        #pragma unroll
        for (int kt2 = 0; kt2 < 2; ++kt2) {
            #pragma unroll
            for (int mt = 0; mt < 4; ++mt) {
                const int R = wm * 64 + mt * 16 + lr;
                bf16x8 a = *reinterpret_cast<const bf16x8*>(
                    Asm[cur] + R * 128 + ((kt2 * 64 + lg * 16) ^ rswz));
                acc[mt][0] = __builtin_amdgcn_mfma_f32_16x16x32_bf16(a, bfr[kt2*4+0], acc[mt][0], 0, 0, 0);
                acc[mt][1] = __builtin_amdgcn_mfma_f32_16x16x32_bf16(a, bfr[kt2*4+1], acc[mt][1], 0, 0, 0);
                acc[mt][2] = __builtin_amdgcn_mfma_f32_16x16x32_bf16(a, bfr[kt2*4+2], acc[mt][2], 0, 0, 0);
                acc[mt][3] = __builtin_amdgcn_mfma_f32_16x16x32_bf16(a, bfr[kt2*4+3], acc[mt][3], 0, 0, 0);
            }
        }
        // 4. cvt + write A(t+1) into the other buffer (vmcnt(0) lands here, after
        //    ~600 cyc of compute has covered most of the A latency)
        if (t + 1 < NSTEP) {
            #pragma unroll
            for (int i = 0; i < 8; ++i) {
                const int r = srow + 16 * i;
                union { __bf16 h[4]; bf16x4 v; } p;
                p.h[0] = (__bf16)rA[i].x; p.h[1] = (__bf16)rA[i].y;
                p.h[2] = (__bf16)rA[i].z; p.h[3] = (__bf16)rA[i].w;
                *reinterpret_cast<bf16x4*>(
                    Asm[cur ^ 1] + r * 128 + ((schk * 8) ^ ((r & 7) << 4))) = p.v;
            }
        }
        __syncthreads();
        cur ^= 1;
    }

    // epilogue: partial score = sum_{n in this 128-col quarter} tanh(acc)*Wf[n]
    float wf[4];
    #pragma unroll
    for (int nt = 0; nt < 4; ++nt) wf[nt] = Wf[ncol0 + nt * 16 + lr];
    #pragma unroll
    for (int mt = 0; mt < 4; ++mt) {
        #pragma unroll
        for (int j = 0; j < 4; ++j) {
            float s = 0.f;
            #pragma unroll
            for (int nt = 0; nt < 4; ++nt) {
                float x = acc[mt][nt][j];
                float e = __expf(2.0f * x);
                float t = 1.0f - 2.0f / (e + 1.0f);   // tanh, no-NaN at +/-inf
                s = fmaf(t, wf[nt], s);
            }
            s += __shfl_xor(s, 1); s += __shfl_xor(s, 2);
            s += __shfl_xor(s, 4); s += __shfl_xor(s, 8);
            if (lr == 0) swave[wn][wm * 64 + mt * 16 + lg * 4 + j] = s;
        }
    }
    __syncthreads();
    if (tid < BM)
        spart[(size_t)nq * MROWS + row0 + tid] = swave[0][tid] + swave[1][tid];
}

// ---------------- softmax over P=196 per batch row (sums 4 N-quarter partials) ----------
__global__ __launch_bounds__(64) void softmax_k(const float* __restrict__ spart,
                                                float* __restrict__ alpha) {
    const int b = blockIdx.x, lane = threadIdx.x;
    float v[4], e[4];
    float m = -3.0e38f;
    #pragma unroll
    for (int i = 0; i < 4; ++i) {
        int p = i * 64 + lane;
        if (p < NP) {
            int idx = b * NP + p;
            v[i] = spart[idx] + spart[MROWS + idx] + spart[2 * MROWS + idx]
                 + spart[3 * MROWS + idx];
        } else v[i] = -3.0e38f;
        m = fmaxf(m, v[i]);
    }
    #pragma unroll
    for (int o = 1; o < 64; o <<= 1) m = fmaxf(m, __shfl_xor(m, o));
    float s = 0.f;
    #pragma unroll
    for (int i = 0; i < 4; ++i) {
        int p = i * 64 + lane;
        e[i] = (p < NP) ? __expf(v[i] - m) : 0.f;
        s += e[i];
    }
    #pragma unroll
    for (int o = 1; o < 64; o <<= 1) s += __shfl_xor(s, o);
    const float inv = 1.0f / s;
    #pragma unroll
    for (int i = 0; i < 4; ++i) {
        int p = i * 64 + lane;
        if (p < NP) alpha[b * NP + p] = e[i] * inv;
    }
}

// ---------------- context[b][f] = sum_p alpha[b][p] * X[b][p][f]  (fp32) ----------------
__global__ __launch_bounds__(128) void context_k(const float* __restrict__ X,
                                                 const float* __restrict__ alpha,
                                                 float* __restrict__ ctx) {
    __shared__ float al[NP];
    const int bid = blockIdx.x;
    const int b = 127 - (bid >> 2);
    const int chunk = bid & 3;
    const int tid = threadIdx.x;
    for (int i = tid; i < NP; i += 128) al[i] = alpha[b * NP + i];
    __syncthreads();
    const float4* Xp = reinterpret_cast<const float4*>(X + (size_t)b * NP * FEAT)
                       + chunk * 128 + tid;
    float4 a0 = {0,0,0,0}, a1 = {0,0,0,0};
    #pragma unroll 4
    for (int p = 0; p < NP; p += 2) {
        const float w0 = al[p], w1 = al[p + 1];
        const float4 x0 = Xp[(size_t)p * 512];
        const float4 x1 = Xp[(size_t)(p + 1) * 512];
        a0.x = fmaf(w0, x0.x, a0.x); a0.y = fmaf(w0, x0.y, a0.y);
        a0.z = fmaf(w0, x0.z, a0.z); a0.w = fmaf(w0, x0.w, a0.w);
        a1.x = fmaf(w1, x1.x, a1.x); a1.y = fmaf(w1, x1.y, a1.y);
        a1.z = fmaf(w1, x1.z, a1.z); a1.w = fmaf(w1, x1.w, a1.w);
    }
    float4 rr; rr.x = a0.x + a1.x; rr.y = a0.y + a1.y; rr.z = a0.z + a1.z; rr.w = a0.w + a1.w;
    *reinterpret_cast<float4*>(ctx + (size_t)b * FEAT + chunk * 512 + tid * 4) = rr;
}

extern "C" void kernel_launch(void* const* d_in, const int* in_sizes, int n_in,
                              void* d_out, int out_size, void* d_ws, size_t ws_size,
                              hipStream_t stream) {
    const float* enc    = (const float*)d_in[0];
    const float* hidden = (const float*)d_in[1];
    const float* We     = (const float*)d_in[2];
    const float* be     = (const float*)d_in[3];
    const float* Wd     = (const float*)d_in[4];
    const float* bd     = (const float*)d_in[5];
    const float* Wf     = (const float*)d_in[6];
    // d_in[7] = bf: additive constant to all scores -> softmax-invariant, unused.

    float* out   = (float*)d_out;
    float* ctx   = out;                  // [128*2048]
    float* alpha = out + NB * FEAT;      // [128*196]

    char* ws = (char*)d_ws;
    __bf16* Bp    = (__bf16*)ws;                                   // 2 MB packed We
    float*  decb  = (float*)(ws + (2u << 20));                     // 256 KB
    float*  spart = (float*)(ws + (2u << 20) + (256u << 10));      // 4 x 100 KB partials

    pack_we_k  <<<dim3(512), dim3(256), 0, stream>>>(We, Bp);
    dec_k      <<<dim3(64),  dim3(256), 0, stream>>>(hidden, Wd, bd, be, decb);
    enc_score_k<<<dim3(NBLK), dim3(256), 0, stream>>>(enc, Bp, decb, Wf, spart);
    softmax_k  <<<dim3(NB),  dim3(64),  0, stream>>>(spart, alpha);
    context_k  <<<dim3(512), dim3(128), 0, stream>>>(enc, alpha, ctx);
}